// Round 1
// baseline (286.293 us; speedup 1.0000x reference)
//
#include <hip/hip_runtime.h>
#include <hip/hip_bf16.h>

// Grouped GEMM: out[n,g,k] = sum_d x[n*8+g, d] * W[g, k, d]
//   x: [65536, 1024] f32, W: [8, 1024, 1024] f32 (torch [k,d] layout == B^T),
//   out: [65536, 1024] f32.
// Structure: m97-class 128x128 tile, BK=64, 4 waves, mfma_f32_16x16x32_bf16,
// fp32->bf16 conversion fused into reg-staging, raw barriers (no vmcnt drain),
// XOR-swizzled LDS, XCD-aware block swizzle (one group per XCD).

namespace {

constexpr int NG   = 8;
constexpr int DIN  = 1024;
constexpr int DOUT = 1024;
constexpr int BM   = 128;
constexpr int BN   = 128;
constexpr int BK   = 64;
constexpr int NKT  = DIN / BK;   // 16 K-tiles

typedef __attribute__((ext_vector_type(8))) short bf16x8;
typedef __attribute__((ext_vector_type(4))) float f32x4;

__device__ __forceinline__ uint2 pack_bf16x4(f32x4 v) {
  union { __hip_bfloat162 h2[2]; uint2 u; } p;
  p.h2[0] = __float22bfloat162_rn(make_float2(v.x, v.y));
  p.h2[1] = __float22bfloat162_rn(make_float2(v.z, v.w));
  return p.u;
}

// compiler fence + wave-LDS-drain + hw barrier (memory clobbers pin LDS ops
// on the correct side; vmcnt is intentionally NOT drained -> reg prefetch
// stays in flight across the barrier)
__device__ __forceinline__ void lds_barrier() {
  asm volatile("s_waitcnt lgkmcnt(0)" ::: "memory");
  __builtin_amdgcn_s_barrier();
  asm volatile("" ::: "memory");
}

__global__ __launch_bounds__(256, 2)
void grouped_gemm_kernel(const float* __restrict__ X,
                         const float* __restrict__ W,
                         float* __restrict__ O) {
  // ---- block mapping: XCD-bijective swizzle (4096 % 8 == 0)
  const int nwg = (int)gridDim.x;            // 4096
  const int cpx = nwg >> 3;                  // 512 blocks per XCD chunk
  const int bid = (int)blockIdx.x;
  const int swz = (bid & 7) * cpx + (bid >> 3);
  const int jt = swz & 7;                    // col tile   [0,8)   (fastest: A-panel reuse)
  const int it = (swz >> 3) & 63;            // row tile   [0,64)
  const int g  = swz >> 9;                   // group      [0,8)   (== XCD id)

  const int n0 = it * BM;                    // token base within group
  const int c0 = jt * BN;                    // output-col base

  const int tid  = (int)threadIdx.x;
  const int lane = tid & 63;
  const int wid  = tid >> 6;                 // wave [0,4): 2x2 wave grid
  const int wr   = wid >> 1;
  const int wc   = wid & 1;

  // staging assignment: 16 lanes per row (float4 each), 16 rows per pass, 8 passes
  const int s_lane = tid & 15;
  const int s_row  = tid >> 4;

  __shared__ __align__(16) short As[BM * BK];   // bf16, XOR-swizzled
  __shared__ __align__(16) short Bs[BN * BK];
  char* const smA = (char*)As;
  char* const smB = (char*)Bs;

  // per-thread global bases. A rows are strided by NG*DIN (group-interleaved).
  const float* Abase = X + (size_t)((n0 + s_row) * NG + g) * DIN + s_lane * 4;
  const float* Bbase = W + (size_t)g * DOUT * DIN + (size_t)(c0 + s_row) * DIN + s_lane * 4;
  constexpr size_t Astride = (size_t)16 * NG * DIN;   // 16 tile-rows per pass
  constexpr size_t Bstride = (size_t)16 * DIN;

  f32x4 aReg[8], bReg[8];
#pragma unroll
  for (int p = 0; p < 8; ++p) {
    aReg[p] = *(const f32x4*)(Abase + p * Astride);
    bReg[p] = *(const f32x4*)(Bbase + p * Bstride);
  }

  f32x4 acc[4][4];
#pragma unroll
  for (int m = 0; m < 4; ++m)
#pragma unroll
    for (int n = 0; n < 4; ++n)
      acc[m][n] = (f32x4){0.f, 0.f, 0.f, 0.f};

  const int fr = lane & 15;   // fragment row-within-16 / output col-within-16
  const int fq = lane >> 4;   // k-chunk selector / output row quad

  for (int kt = 0; kt < NKT; ++kt) {
    // ---- barrier A: every wave's LDS reads from previous tile are complete
    lds_barrier();

    // ---- convert + stage k-tile kt (already in regs) into LDS as bf16
#pragma unroll
    for (int p = 0; p < 8; ++p) {
      const int row = s_row + p * 16;
      const int wb  = (row * (BK * 2) + s_lane * 8) ^ ((row & 7) << 4);
      *(uint2*)(smA + wb) = pack_bf16x4(aReg[p]);
      *(uint2*)(smB + wb) = pack_bf16x4(bReg[p]);
    }

    // ---- barrier B: tile visible to all waves
    lds_barrier();

    // ---- prefetch k-tile kt+1 into regs; left in flight during compute
    if (kt + 1 < NKT) {
      const float* An = Abase + (size_t)(kt + 1) * BK;
      const float* Bn = Bbase + (size_t)(kt + 1) * BK;
#pragma unroll
      for (int p = 0; p < 8; ++p) {
        aReg[p] = *(const f32x4*)(An + p * Astride);
        bReg[p] = *(const f32x4*)(Bn + p * Bstride);
      }
    }

    // ---- compute: 2 k-subtiles of 32, 4x4 fragments per wave
#pragma unroll
    for (int ks = 0; ks < 2; ++ks) {
      bf16x8 af[4], bfr[4];
#pragma unroll
      for (int m = 0; m < 4; ++m) {
        const int row = wr * 64 + m * 16 + fr;
        af[m] = *(const bf16x8*)(smA +
            ((row * (BK * 2) + ks * 64 + fq * 16) ^ ((row & 7) << 4)));
      }
#pragma unroll
      for (int n = 0; n < 4; ++n) {
        const int row = wc * 64 + n * 16 + fr;
        bfr[n] = *(const bf16x8*)(smB +
            ((row * (BK * 2) + ks * 64 + fq * 16) ^ ((row & 7) << 4)));
      }
#pragma unroll
      for (int m = 0; m < 4; ++m)
#pragma unroll
        for (int n = 0; n < 4; ++n)
          acc[m][n] = __builtin_amdgcn_mfma_f32_16x16x32_bf16(
              af[m], bfr[n], acc[m][n], 0, 0, 0);
    }
  }

  // ---- epilogue: C/D layout col = lane&15, row = (lane>>4)*4 + reg (m89)
#pragma unroll
  for (int m = 0; m < 4; ++m) {
#pragma unroll
    for (int r = 0; r < 4; ++r) {
      const int lr = wr * 64 + m * 16 + fq * 4 + r;
      float* orow = O + (size_t)((n0 + lr) * NG + g) * DOUT + c0;
#pragma unroll
      for (int n = 0; n < 4; ++n) {
        orow[wc * 64 + n * 16 + fr] = acc[m][n][r];
      }
    }
  }
}

} // namespace

extern "C" void kernel_launch(void* const* d_in, const int* in_sizes, int n_in,
                              void* d_out, int out_size, void* d_ws, size_t ws_size,
                              hipStream_t stream) {
  (void)n_in; (void)d_ws; (void)ws_size; (void)out_size;
  const float* X = (const float*)d_in[0];
  const float* W = (const float*)d_in[1];
  float* O = (float*)d_out;

  const int tokens_total = in_sizes[0] / DIN;            // 65536
  const int ntok_per_g   = tokens_total / NG;            // 8192
  const int grid = NG * (ntok_per_g / BM) * (DOUT / BN); // 4096

  grouped_gemm_kernel<<<dim3(grid), dim3(256), 0, stream>>>(X, W, O);
}

// Round 2
// 266.352 us; speedup vs baseline: 1.0749x; 1.0749x over previous
//
#include <hip/hip_runtime.h>
#include <hip/hip_bf16.h>

// Grouped GEMM: out[n,g,k] = sum_d x[n*8+g, d] * W[g, k, d]
// 256x256 tile, BK=64, 8 waves (2Mx4N), 4-phase/K-step interleaved schedule
// (T3+T4), double-buffered 128KiB LDS, fp32->bf16 cvt fused into reg-staging,
// XOR-swizzled LDS (T2), setprio around MFMA (T5), group-per-XCD swizzle (T1).

namespace {

constexpr int NG   = 8;
constexpr int DIN  = 1024;
constexpr int DOUT = 1024;
constexpr int BM   = 256;
constexpr int BN   = 256;
constexpr int BK   = 64;
constexpr int NKT  = DIN / BK;            // 16
constexpr int ROWB = BK * 2;              // 128 B per LDS row
constexpr int LDS_TILE  = BM * ROWB;      // 32 KiB per tile buffer
constexpr int LDS_BYTES = 4 * LDS_TILE;   // 128 KiB: A0,A1,B0,B1

typedef __attribute__((ext_vector_type(8))) short bf16x8;
typedef __attribute__((ext_vector_type(4))) float f32x4;

__device__ __forceinline__ uint2 pack_bf16x4(f32x4 v) {
  union { __hip_bfloat162 h2[2]; uint2 u; } p;
  p.h2[0] = __float22bfloat162_rn(make_float2(v.x, v.y));
  p.h2[1] = __float22bfloat162_rn(make_float2(v.z, v.w));
  return p.u;
}

#define FENCE() asm volatile("" ::: "memory")
#define BAR()   do { FENCE(); __builtin_amdgcn_s_barrier(); FENCE(); } while (0)
#define LGKM0() asm volatile("s_waitcnt lgkmcnt(0)" ::: "memory")

// one phase: ds_read A-quad Q -> [PRE staging ops] -> barrier -> lgkm(0) ->
// setprio(1) -> 16 MFMA -> setprio(0) -> [POST staging ops] -> barrier
#define QPHASE(Q, PRE, POST)                                                   \
  do {                                                                         \
    bf16x8 a0k0 = *(const bf16x8*)(cA + aRow0 + (2*(Q))   * 2048 + colx0);     \
    bf16x8 a0k1 = *(const bf16x8*)(cA + aRow0 + (2*(Q))   * 2048 + colx1);     \
    bf16x8 a1k0 = *(const bf16x8*)(cA + aRow0 + (2*(Q)+1) * 2048 + colx0);     \
    bf16x8 a1k1 = *(const bf16x8*)(cA + aRow0 + (2*(Q)+1) * 2048 + colx1);     \
    PRE                                                                        \
    BAR();                                                                     \
    LGKM0();                                                                   \
    __builtin_amdgcn_sched_barrier(0);                                         \
    __builtin_amdgcn_s_setprio(1);                                             \
    _Pragma("unroll")                                                          \
    for (int n = 0; n < 4; ++n) {                                              \
      acc[2*(Q)][n]   = __builtin_amdgcn_mfma_f32_16x16x32_bf16(               \
          a0k0, bfr[n][0], acc[2*(Q)][n],   0, 0, 0);                          \
      acc[2*(Q)][n]   = __builtin_amdgcn_mfma_f32_16x16x32_bf16(               \
          a0k1, bfr[n][1], acc[2*(Q)][n],   0, 0, 0);                          \
      acc[2*(Q)+1][n] = __builtin_amdgcn_mfma_f32_16x16x32_bf16(               \
          a1k0, bfr[n][0], acc[2*(Q)+1][n], 0, 0, 0);                          \
      acc[2*(Q)+1][n] = __builtin_amdgcn_mfma_f32_16x16x32_bf16(               \
          a1k1, bfr[n][1], acc[2*(Q)+1][n], 0, 0, 0);                          \
    }                                                                          \
    __builtin_amdgcn_s_setprio(0);                                             \
    POST                                                                       \
    BAR();                                                                     \
  } while (0)

__global__ __launch_bounds__(512, 2)
void grouped_gemm_8p(const float* __restrict__ X,
                     const float* __restrict__ W,
                     float* __restrict__ O) {
  extern __shared__ char smem[];
  char* const smA = smem;                  // [2][256][64] bf16, swizzled
  char* const smB = smem + 2 * LDS_TILE;

  // ---- block mapping: group == XCD (1024 blocks, 128/XCD-chunk), bijective
  const int bid = (int)blockIdx.x;
  const int swz = (bid & 7) * 128 + (bid >> 3);
  const int jt = swz & 3;                  // col tile  [0,4)  fastest: A reuse
  const int it = (swz >> 2) & 31;          // row tile  [0,32)
  const int g  = swz >> 7;                 // group     [0,8)  == XCD

  const int n0 = it * BM;                  // token base within group
  const int c0 = jt * BN;                  // output-col base

  const int tid  = (int)threadIdx.x;
  const int lane = tid & 63;
  const int wid  = tid >> 6;               // 8 waves: 2(M) x 4(N)
  const int wr   = wid >> 2;
  const int wc   = wid & 3;

  // staging map: 16 lanes x float4 = 64 cols; 32 rows/pass; 8 passes
  const int s_lane = tid & 15;
  const int s_row  = tid >> 4;

  const float* Ag = X + ((size_t)(n0 + s_row) * NG + g) * DIN + s_lane * 4;
  const float* Bg = W + (size_t)g * DOUT * DIN + (size_t)(c0 + s_row) * DIN
                      + s_lane * 4;
  constexpr size_t ASTR = (size_t)32 * NG * DIN;   // 32 tile-rows per pass
  constexpr size_t BSTR = (size_t)32 * DIN;

  // swizzled LDS write base (row&7 invariant across passes: 32 % 8 == 0)
  const int wb0 = s_row * ROWB + ((s_lane * 8) ^ ((s_row & 7) << 4));

  // fragment addressing (row&7 == fr&7 for all frag rows)
  const int fr = lane & 15;
  const int fq = lane >> 4;
  const int swzm  = (fr & 7) << 4;
  const int colx0 = (fq * 16) ^ swzm;          // ks=0
  const int colx1 = (64 + fq * 16) ^ swzm;     // ks=1
  const int aRow0 = (wr * 128 + fr) * ROWB;
  const int bRow0 = (wc * 64  + fr) * ROWB;

  f32x4 aS[8], bS[8];
  f32x4 acc[8][4];
#pragma unroll
  for (int m = 0; m < 8; ++m)
#pragma unroll
    for (int n = 0; n < 4; ++n) acc[m][n] = (f32x4){0.f, 0.f, 0.f, 0.f};

  // ---- prologue: stage tile 0 into buffer 0
#pragma unroll
  for (int p = 0; p < 8; ++p) {
    aS[p] = *(const f32x4*)(Ag + p * ASTR);
    bS[p] = *(const f32x4*)(Bg + p * BSTR);
  }
#pragma unroll
  for (int p = 0; p < 8; ++p) {
    *(uint2*)(smA + wb0 + p * 4096) = pack_bf16x4(aS[p]);
    *(uint2*)(smB + wb0 + p * 4096) = pack_bf16x4(bS[p]);
  }
  LGKM0();
  BAR();

#pragma unroll 2
  for (int t = 0; t < NKT; ++t) {
    char* const cA = smA + (t & 1) * LDS_TILE;
    char* const cB = smB + (t & 1) * LDS_TILE;
    char* const nA = smA + ((t & 1) ^ 1) * LDS_TILE;
    char* const nB = smB + ((t & 1) ^ 1) * LDS_TILE;
    const bool stage = (t + 1) < NKT;

    // B fragments for the whole K-step (held in regs across all 4 phases)
    bf16x8 bfr[4][2];
#pragma unroll
    for (int n = 0; n < 4; ++n) {
      bfr[n][0] = *(const bf16x8*)(cB + bRow0 + n * 2048 + colx0);
      bfr[n][1] = *(const bf16x8*)(cB + bRow0 + n * 2048 + colx1);
    }

    // P0: + issue A-loads(t+1)            (consumed post-MFMA P1: ~1.7 phases)
    QPHASE(0,
      { if (stage) {
          const float* An = Ag + (size_t)(t + 1) * BK;
          for (int p = 0; p < 8; ++p) aS[p] = *(const f32x4*)(An + p * ASTR);
        } },
      { });

    // P1: + cvt/write A(t+1) after MFMA   (drained by P2's lgkm(0))
    QPHASE(1, { },
      { if (stage) {
          for (int p = 0; p < 8; ++p)
            *(uint2*)(nA + wb0 + p * 4096) = pack_bf16x4(aS[p]);
        } });

    // P2: + issue B-loads(t+1)            (W is XCD-L2-resident: short latency)
    QPHASE(2,
      { if (stage) {
          const float* Bn = Bg + (size_t)(t + 1) * BK;
          for (int p = 0; p < 8; ++p) bS[p] = *(const f32x4*)(Bn + p * BSTR);
        } },
      { });

    // P3: + cvt/write B(t+1) after MFMA; drain own writes before swap barrier
    QPHASE(3, { },
      { if (stage) {
          for (int p = 0; p < 8; ++p)
            *(uint2*)(nB + wb0 + p * 4096) = pack_bf16x4(bS[p]);
        }
        LGKM0(); });
  }

  // ---- epilogue: C/D layout col = lane&15, row = (lane>>4)*4 + reg (m89)
#pragma unroll
  for (int m = 0; m < 8; ++m) {
#pragma unroll
    for (int r = 0; r < 4; ++r) {
      const int row = wr * 128 + m * 16 + fq * 4 + r;
      float* orow = O + ((size_t)(n0 + row) * NG + g) * DOUT + c0 + wc * 64;
#pragma unroll
      for (int n = 0; n < 4; ++n) {
        orow[n * 16 + fr] = acc[m][n][r];
      }
    }
  }
}

} // namespace

extern "C" void kernel_launch(void* const* d_in, const int* in_sizes, int n_in,
                              void* d_out, int out_size, void* d_ws, size_t ws_size,
                              hipStream_t stream) {
  (void)n_in; (void)d_ws; (void)ws_size; (void)out_size;
  const float* X = (const float*)d_in[0];
  const float* W = (const float*)d_in[1];
  float* O = (float*)d_out;

  const int tokens_total = in_sizes[0] / DIN;            // 65536
  const int ntok_per_g   = tokens_total / NG;            // 8192
  const int grid = NG * (ntok_per_g / BM) * (DOUT / BN); // 1024

  // 128 KiB dynamic LDS needs the opt-in attribute (host-side, capture-safe)
  (void)hipFuncSetAttribute((const void*)grouped_gemm_8p,
                            hipFuncAttributeMaxDynamicSharedMemorySize,
                            LDS_BYTES);

  grouped_gemm_8p<<<dim3(grid), dim3(512), LDS_BYTES, stream>>>(X, W, O);
}